// Round 10
// baseline (274.496 us; speedup 1.0000x reference)
//
#include <hip/hip_runtime.h>

// ChamferLoss: B=4, C=3, N=M=8192 fp32.
// loss = 2 * mean_b( sum_n min_m ||q_n - r_m||^2 ), clamp >= 0.
// s(n,m) = q.r - 0.5*r^2 via v_mfma_f32_32x32x16_bf16, fp32 split as bf16
// hi+lo across K. Fragment bits identical to R10-R19 (verified absmax 0.0).
//
// ROUND 20: CLOCK PROBE round. R19 (134MB->9MB traffic) changed nothing:
// main ~18us regardless of load schedule (R12/13/14), store class (R18),
// or volume/source (R19). Careful pipe model at 2.4GHz: MFMA 3.4us ||
// VALU 3.4us => ~3.5-7us. The uniform 2.6-5x gap across ALL structures
// (incl. R16's +10.3us for +4.3us of modeled VALU) fits ONE hypothesis:
// core clock << 2.4GHz (55% of each iteration is memory fill; 18us
// compute bursts may never ramp DVFS). R17 only proved clocks steady,
// not high. Probe: 1-block/64-thread kernel, ~270K-cycle serial FMA
// chain; dur = 270K/f_core, lands in rocprof top-5 (>40.5us always),
// identifiable by Workgroup_Size=64.
//   ~105-120us  -> full clock -> main is structural, attack MFMA dep next
//   >=220us     -> f=270000/dur MHz -> DVFS floor -> declare roofline
// R19 kernels byte-identical below; probe appended last (1 CU, no
// interference with the timed compute).

#define NPTS 8192
#define NB   4
#define RRN  8        // ref ranges (1024 refs each)
#define QGN  16       // q-chunk groups per batch (16 q-chunks each)
#define BT   512

typedef float f32x16 __attribute__((ext_vector_type(16)));
typedef short bf16x8 __attribute__((ext_vector_type(8)));

static __device__ __forceinline__ unsigned int f2bf(float f) {
    unsigned int u = __float_as_uint(f);
    u += 0x7FFF + ((u >> 16) & 1);          // RNE
    return u >> 16;
}
static __device__ __forceinline__ float bf2f(unsigned int s) {
    return __uint_as_float(s << 16);
}

static __device__ __forceinline__ bf16x8 make_bfrag(float x, float y, float z,
                                                    int lane)
{
    unsigned xh = f2bf(x), yh = f2bf(y), zh = f2bf(z);
    unsigned xl = f2bf(x - bf2f(xh));
    unsigned yl = f2bf(y - bf2f(yh));
    unsigned zl = f2bf(z - bf2f(zh));
    // B k0..7 = [xh,xh,xl,yh,yh,yl,zh,zh], k8..15 = [zl,1,1,0,...]
    uint4 bu = (lane < 32)
        ? make_uint4(xh | (xh << 16), xl | (yh << 16),
                     yh | (yl << 16), zh | (zh << 16))
        : make_uint4(zl | (0x3F80u << 16), 0x3F80u, 0u, 0u);
    return __builtin_bit_cast(bf16x8, bu);
}

static __device__ __forceinline__ void proc_chunk(
    uint4 av, bf16x8 bq0, bf16x8 bq1, const f32x16& zero,
    float& rma0, float& rma1, float& rma2, float& rma3,
    float& rmb0, float& rmb1, float& rmb2, float& rmb3)
{
    bf16x8 aa = __builtin_bit_cast(bf16x8, av);
    f32x16 d0 = __builtin_amdgcn_mfma_f32_32x32x16_bf16(aa, bq0, zero, 0, 0, 0);
    f32x16 d1 = __builtin_amdgcn_mfma_f32_32x32x16_bf16(aa, bq1, zero, 0, 0, 0);
    // each line is a 3-input max -> v_max3_f32
    rma0 = fmaxf(rma0, fmaxf(d0[0],  d0[1]));   // rows = refs
    rma0 = fmaxf(rma0, fmaxf(d0[2],  d0[3]));
    rma1 = fmaxf(rma1, fmaxf(d0[4],  d0[5]));
    rma1 = fmaxf(rma1, fmaxf(d0[6],  d0[7]));
    rma2 = fmaxf(rma2, fmaxf(d0[8],  d0[9]));
    rma2 = fmaxf(rma2, fmaxf(d0[10], d0[11]));
    rma3 = fmaxf(rma3, fmaxf(d0[12], d0[13]));
    rma3 = fmaxf(rma3, fmaxf(d0[14], d0[15]));
    rmb0 = fmaxf(rmb0, fmaxf(d1[0],  d1[1]));
    rmb0 = fmaxf(rmb0, fmaxf(d1[2],  d1[3]));
    rmb1 = fmaxf(rmb1, fmaxf(d1[4],  d1[5]));
    rmb1 = fmaxf(rmb1, fmaxf(d1[6],  d1[7]));
    rmb2 = fmaxf(rmb2, fmaxf(d1[8],  d1[9]));
    rmb2 = fmaxf(rmb2, fmaxf(d1[10], d1[11]));
    rmb3 = fmaxf(rmb3, fmaxf(d1[12], d1[13]));
    rmb3 = fmaxf(rmb3, fmaxf(d1[14], d1[15]));
}

// ---- K1: shared-A main kernel ----
// grid (QGN, RRN, NB) = (16,8,4) = 512 blocks = 2/CU, one round.
__global__ __launch_bounds__(BT, 4) void chamfer_main(
    const float* __restrict__ pc2,       // queries [B,3,N]
    const float* __restrict__ pc1w,      // refs    [B,3,N]
    float* __restrict__ partial,         // [B][RRN][NPTS] in ws (1 MiB)
    float* __restrict__ out)
{
    __shared__ uint4 slds[32 * 64];      // 32 KB: A-fragments for 1024 refs
    const int tid  = threadIdx.x;
    const int wave = tid >> 6;
    const int lane = tid & 63;
    const int b    = blockIdx.z;
    const int rr   = blockIdx.y;
    const int qg   = blockIdx.x;

    // zero the accumulator for K2's atomics (K2 is a later dispatch ->
    // stream-ordered; pattern verified in R10)
    if (qg == 0 && rr == 0 && b == 0 && tid == 0) out[0] = 0.0f;

    // stage + convert this range's 1024 refs into A-fragment layout
    // (bit-identical to R11's verified staging conversion)
    const float* refb = pc1w + b * 3 * NPTS + rr * 1024;
#pragma unroll
    for (int j = 0; j < 2; ++j) {
        int i = tid + j * BT;            // 0..1023, coalesced
        float x = refb[i], y = refb[NPTS + i], z = refb[2 * NPTS + i];
        unsigned xh = f2bf(x), yh = f2bf(y), zh = f2bf(z);
        unsigned xl = f2bf(x - bf2f(xh));
        unsigned yl = f2bf(y - bf2f(yh));
        unsigned zl = f2bf(z - bf2f(zh));
        float h = -0.5f * (x * x + y * y + z * z);
        unsigned hh = f2bf(h);
        unsigned hl = f2bf(h - bf2f(hh));
        int c = i >> 5, l32 = i & 31;
        // A k0..7 = [xh,xl,xh,yh,yl,yh,zh,zl], k8..15 = [zh,hh,hl,0,...]
        slds[c * 64 + l32] =
            make_uint4(xh | (xl << 16), xh | (yh << 16),
                       yl | (yh << 16), zh | (zl << 16));
        slds[c * 64 + 32 + l32] = make_uint4(zh | (hh << 16), hl, 0u, 0u);
    }

    // this wave's 2 query chunks (of the block's 16)
    const int qc0 = qg * 16 + wave * 2;
    const float* qb = pc2 + b * 3 * NPTS;
    const int qn0 = qc0 * 32 + (lane & 31);
    const int qn1 = qn0 + 32;
    float x0 = qb[qn0], y0 = qb[NPTS + qn0], z0 = qb[2 * NPTS + qn0];
    float x1 = qb[qn1], y1 = qb[NPTS + qn1], z1 = qb[2 * NPTS + qn1];
    bf16x8 bq0 = make_bfrag(x0, y0, z0, lane);
    bf16x8 bq1 = make_bfrag(x1, y1, z1, lane);

    f32x16 zero;
#pragma unroll
    for (int i = 0; i < 16; ++i) zero[i] = 0.0f;

    float rma0 = -3e38f, rma1 = -3e38f, rma2 = -3e38f, rma3 = -3e38f;
    float rmb0 = -3e38f, rmb1 = -3e38f, rmb2 = -3e38f, rmb3 = -3e38f;

    __syncthreads();                     // LDS image complete

    // all 8 waves share the same 32 chunks; ds_read 1 ahead
    uint4 av = slds[lane];
#pragma unroll 4
    for (int c = 0; c < 32; ++c) {
        uint4 acur = av;
        if (c + 1 < 32)
            av = slds[(c + 1) * 64 + lane];
        proc_chunk(acur, bq0, bq1, zero, rma0, rma1, rma2, rma3,
                   rmb0, rmb1, rmb2, rmb3);
    }

    float rma = fmaxf(fmaxf(rma0, rma1), fmaxf(rma2, rma3));
    float rmb = fmaxf(fmaxf(rmb0, rmb1), fmaxf(rmb2, rmb3));
    // lanes l and l^32 hold the two row-halves of the same query column
    rma = fmaxf(rma, __shfl_xor(rma, 32, 64));
    rmb = fmaxf(rmb, __shfl_xor(rmb, 32, 64));
    float* pb = partial + ((size_t)b * RRN + rr) * NPTS + qc0 * 32;
    if (lane < 32) {
        pb[lane]      = rma;
        pb[32 + lane] = rmb;
    }
}

// ---- K2: finalize (verified R10 structure) ----
__global__ __launch_bounds__(512) void chamfer_reduce(
    const float* __restrict__ pc2,
    const float* __restrict__ partial,
    float* __restrict__ out)
{
    const int g = blockIdx.x * 512 + threadIdx.x;   // query id
    const int b = g >> 13, n = g & 8191;
    float smax = -3e38f;
#pragma unroll
    for (int c = 0; c < RRN; ++c)
        smax = fmaxf(smax, partial[((size_t)b * RRN + c) * NPTS + n]);

    const float* qb = pc2 + b * 3 * NPTS;
    float qx = qb[n], qy = qb[NPTS + n], qz = qb[2 * NPTS + n];
    float q2 = qx * qx + qy * qy + qz * qz;
    float d = fmaxf(q2 - 2.0f * smax, 0.0f);

#pragma unroll
    for (int off = 32; off > 0; off >>= 1)
        d += __shfl_down(d, off, 64);

    __shared__ float wsum[8];
    const int lane = threadIdx.x & 63;
    const int wid  = threadIdx.x >> 6;
    if (lane == 0) wsum[wid] = d;
    __syncthreads();
    if (threadIdx.x == 0) {
        float s = 0.0f;
#pragma unroll
        for (int w = 0; w < 8; ++w) s += wsum[w];
        atomicAdd(out, s * (2.0f / NB));   // 2 * mean over batches
    }
}

// ---- CLOCK PROBE: ~270K-cycle serial FMA chain; dur_us = 270000/f_MHz.
// 1 block / 64 threads (Workgroup_Size=64 identifies it in top-5).
// Reads/writes only ws scratch; cannot affect out.
__global__ __launch_bounds__(64) void clock_probe(float* sink)
{
    float a = sink[64];                  // runtime poison value, no folding
    const float b = 1.0000001f, c = 1e-9f;
#pragma unroll 1
    for (int i = 0; i < 7500; ++i) {     // 7500 x 8 = 60000 dependent FMAs
        a = __builtin_fmaf(a, b, c);
        a = __builtin_fmaf(a, b, c);
        a = __builtin_fmaf(a, b, c);
        a = __builtin_fmaf(a, b, c);
        a = __builtin_fmaf(a, b, c);
        a = __builtin_fmaf(a, b, c);
        a = __builtin_fmaf(a, b, c);
        a = __builtin_fmaf(a, b, c);
    }
    if (threadIdx.x == 0) sink[0] = a;   // keep the chain live
}

extern "C" void kernel_launch(void* const* d_in, const int* in_sizes, int n_in,
                              void* d_out, int out_size, void* d_ws, size_t ws_size,
                              hipStream_t stream) {
    const float* pc2  = (const float*)d_in[0];
    const float* pc1w = (const float*)d_in[1];
    float* out = (float*)d_out;
    float* partial = (float*)d_ws;       // B * RRN * NPTS * 4 = 1 MiB
    float* scratch = (float*)((char*)d_ws + (2u << 20));   // probe sink

    dim3 g1(QGN, RRN, NB);               // (16,8,4) = 512 blocks = 2/CU
    chamfer_main<<<g1, BT, 0, stream>>>(pc2, pc1w, partial, out);
    chamfer_reduce<<<NB * NPTS / 512, 512, 0, stream>>>(pc2, partial, out);
    clock_probe<<<1, 64, 0, stream>>>(scratch);
}

// Round 11
// 138.415 us; speedup vs baseline: 1.9831x; 1.9831x over previous
//
#include <hip/hip_runtime.h>

// ChamferLoss: B=4, C=3, N=M=8192 fp32.
// loss = 2 * mean_b( sum_n min_m ||q_n - r_m||^2 ), clamp >= 0.
// s(n,m) = q.r - 0.5*r^2 via v_mfma_f32_32x32x16_bf16, fp32 split as bf16
// hi+lo across K. Fragment bits identical to R10-R19 (verified absmax 0.0).
//
// ROUND 21: fuse the reduce via last-block-arrival; probe removed.
// R20 clock probe: 202us for a ~250-270K-cycle serial FMA chain => core
// clock ~1.2-1.3 GHz (NOT 2.4). All prior pipe models were ~1.85x
// optimistic; main's floor at real clock is ~10-12us vs ~18 measured --
// the residual 1.5x resisted 8 structural variants, low EV. Remaining
// lever: dispatch count. K2 folded into K1: after writing partials each
// block does __threadfence + atomicAdd on counter[b][qg]; the 8th
// arrival re-fences, reduces its (b,qg)'s 512 queries over the 8 rr
// partials, and atomicAdds the block sum to out. Deletes the K2 dispatch
// + its graph-node gap (~4-6us predicted). out + counters zeroed by
// stream-ordered hipMemsetAsync (R16-proven pattern; avoids R15's race).
// Main loop byte-identical to R19.
//   dur 73.6 -> ~67-70 expected; on FAIL/null: revert to R19, declare.

#define NPTS 8192
#define NB   4
#define RRN  8        // ref ranges (1024 refs each)
#define QGN  16       // q-chunk groups per batch (16 q-chunks each)
#define BT   512

typedef float f32x16 __attribute__((ext_vector_type(16)));
typedef short bf16x8 __attribute__((ext_vector_type(8)));

static __device__ __forceinline__ unsigned int f2bf(float f) {
    unsigned int u = __float_as_uint(f);
    u += 0x7FFF + ((u >> 16) & 1);          // RNE
    return u >> 16;
}
static __device__ __forceinline__ float bf2f(unsigned int s) {
    return __uint_as_float(s << 16);
}

static __device__ __forceinline__ bf16x8 make_bfrag(float x, float y, float z,
                                                    int lane)
{
    unsigned xh = f2bf(x), yh = f2bf(y), zh = f2bf(z);
    unsigned xl = f2bf(x - bf2f(xh));
    unsigned yl = f2bf(y - bf2f(yh));
    unsigned zl = f2bf(z - bf2f(zh));
    // B k0..7 = [xh,xh,xl,yh,yh,yl,zh,zh], k8..15 = [zl,1,1,0,...]
    uint4 bu = (lane < 32)
        ? make_uint4(xh | (xh << 16), xl | (yh << 16),
                     yh | (yl << 16), zh | (zh << 16))
        : make_uint4(zl | (0x3F80u << 16), 0x3F80u, 0u, 0u);
    return __builtin_bit_cast(bf16x8, bu);
}

static __device__ __forceinline__ void proc_chunk(
    uint4 av, bf16x8 bq0, bf16x8 bq1, const f32x16& zero,
    float& rma0, float& rma1, float& rma2, float& rma3,
    float& rmb0, float& rmb1, float& rmb2, float& rmb3)
{
    bf16x8 aa = __builtin_bit_cast(bf16x8, av);
    f32x16 d0 = __builtin_amdgcn_mfma_f32_32x32x16_bf16(aa, bq0, zero, 0, 0, 0);
    f32x16 d1 = __builtin_amdgcn_mfma_f32_32x32x16_bf16(aa, bq1, zero, 0, 0, 0);
    // each line is a 3-input max -> v_max3_f32
    rma0 = fmaxf(rma0, fmaxf(d0[0],  d0[1]));   // rows = refs
    rma0 = fmaxf(rma0, fmaxf(d0[2],  d0[3]));
    rma1 = fmaxf(rma1, fmaxf(d0[4],  d0[5]));
    rma1 = fmaxf(rma1, fmaxf(d0[6],  d0[7]));
    rma2 = fmaxf(rma2, fmaxf(d0[8],  d0[9]));
    rma2 = fmaxf(rma2, fmaxf(d0[10], d0[11]));
    rma3 = fmaxf(rma3, fmaxf(d0[12], d0[13]));
    rma3 = fmaxf(rma3, fmaxf(d0[14], d0[15]));
    rmb0 = fmaxf(rmb0, fmaxf(d1[0],  d1[1]));
    rmb0 = fmaxf(rmb0, fmaxf(d1[2],  d1[3]));
    rmb1 = fmaxf(rmb1, fmaxf(d1[4],  d1[5]));
    rmb1 = fmaxf(rmb1, fmaxf(d1[6],  d1[7]));
    rmb2 = fmaxf(rmb2, fmaxf(d1[8],  d1[9]));
    rmb2 = fmaxf(rmb2, fmaxf(d1[10], d1[11]));
    rmb3 = fmaxf(rmb3, fmaxf(d1[12], d1[13]));
    rmb3 = fmaxf(rmb3, fmaxf(d1[14], d1[15]));
}

// ---- fused kernel: shared-A main + last-block-arrival reduce ----
// grid (QGN, RRN, NB) = (16,8,4) = 512 blocks = 2/CU, one round.
__global__ __launch_bounds__(BT, 4) void chamfer_fused(
    const float* __restrict__ pc2,       // queries [B,3,N]
    const float* __restrict__ pc1w,      // refs    [B,3,N]
    float* __restrict__ partial,         // [B][RRN][NPTS] in ws (1 MiB)
    int*   __restrict__ counter,         // [B][QGN] zeroed by memsetAsync
    float* __restrict__ out)             // zeroed by memsetAsync
{
    __shared__ uint4 slds[32 * 64];      // 32 KB: A-fragments for 1024 refs
    const int tid  = threadIdx.x;
    const int wave = tid >> 6;
    const int lane = tid & 63;
    const int b    = blockIdx.z;
    const int rr   = blockIdx.y;
    const int qg   = blockIdx.x;

    // stage + convert this range's 1024 refs into A-fragment layout
    // (bit-identical to R11/R19's verified staging conversion)
    const float* refb = pc1w + b * 3 * NPTS + rr * 1024;
#pragma unroll
    for (int j = 0; j < 2; ++j) {
        int i = tid + j * BT;            // 0..1023, coalesced
        float x = refb[i], y = refb[NPTS + i], z = refb[2 * NPTS + i];
        unsigned xh = f2bf(x), yh = f2bf(y), zh = f2bf(z);
        unsigned xl = f2bf(x - bf2f(xh));
        unsigned yl = f2bf(y - bf2f(yh));
        unsigned zl = f2bf(z - bf2f(zh));
        float h = -0.5f * (x * x + y * y + z * z);
        unsigned hh = f2bf(h);
        unsigned hl = f2bf(h - bf2f(hh));
        int c = i >> 5, l32 = i & 31;
        // A k0..7 = [xh,xl,xh,yh,yl,yh,zh,zl], k8..15 = [zh,hh,hl,0,...]
        slds[c * 64 + l32] =
            make_uint4(xh | (xl << 16), xh | (yh << 16),
                       yl | (yh << 16), zh | (zl << 16));
        slds[c * 64 + 32 + l32] = make_uint4(zh | (hh << 16), hl, 0u, 0u);
    }

    // this wave's 2 query chunks (of the block's 16)
    const int qc0 = qg * 16 + wave * 2;
    const float* qb = pc2 + b * 3 * NPTS;
    const int qn0 = qc0 * 32 + (lane & 31);
    const int qn1 = qn0 + 32;
    float x0 = qb[qn0], y0 = qb[NPTS + qn0], z0 = qb[2 * NPTS + qn0];
    float x1 = qb[qn1], y1 = qb[NPTS + qn1], z1 = qb[2 * NPTS + qn1];
    bf16x8 bq0 = make_bfrag(x0, y0, z0, lane);
    bf16x8 bq1 = make_bfrag(x1, y1, z1, lane);

    f32x16 zero;
#pragma unroll
    for (int i = 0; i < 16; ++i) zero[i] = 0.0f;

    float rma0 = -3e38f, rma1 = -3e38f, rma2 = -3e38f, rma3 = -3e38f;
    float rmb0 = -3e38f, rmb1 = -3e38f, rmb2 = -3e38f, rmb3 = -3e38f;

    __syncthreads();                     // LDS image complete

    // all 8 waves share the same 32 chunks; ds_read 1 ahead
    uint4 av = slds[lane];
#pragma unroll 4
    for (int c = 0; c < 32; ++c) {
        uint4 acur = av;
        if (c + 1 < 32)
            av = slds[(c + 1) * 64 + lane];
        proc_chunk(acur, bq0, bq1, zero, rma0, rma1, rma2, rma3,
                   rmb0, rmb1, rmb2, rmb3);
    }

    float rma = fmaxf(fmaxf(rma0, rma1), fmaxf(rma2, rma3));
    float rmb = fmaxf(fmaxf(rmb0, rmb1), fmaxf(rmb2, rmb3));
    // lanes l and l^32 hold the two row-halves of the same query column
    rma = fmaxf(rma, __shfl_xor(rma, 32, 64));
    rmb = fmaxf(rmb, __shfl_xor(rmb, 32, 64));
    float* pb = partial + ((size_t)b * RRN + rr) * NPTS + qc0 * 32;
    if (lane < 32) {
        pb[lane]      = rma;
        pb[32 + lane] = rmb;
    }

    // ---- last-block-arrival reduce for this (b, qg) ----
    __threadfence();                     // release our partial writes
    __shared__ int amlast;
    if (tid == 0) {
        int prev = atomicAdd(&counter[b * QGN + qg], 1);
        amlast = (prev == RRN - 1);
    }
    __syncthreads();
    if (!amlast) return;
    __threadfence();                     // acquire other blocks' partials

    const int n = qg * 512 + tid;        // this (b,qg)'s 512 queries
    float smax = -3e38f;
#pragma unroll
    for (int c = 0; c < RRN; ++c)
        smax = fmaxf(smax, partial[((size_t)b * RRN + c) * NPTS + n]);

    float qx = qb[n], qy = qb[NPTS + n], qz = qb[2 * NPTS + n];
    float d = fmaxf(qx * qx + qy * qy + qz * qz - 2.0f * smax, 0.0f);

#pragma unroll
    for (int off = 32; off > 0; off >>= 1)
        d += __shfl_down(d, off, 64);

    __shared__ float wsum[8];
    if (lane == 0) wsum[wave] = d;
    __syncthreads();
    if (tid == 0) {
        float s = 0.0f;
#pragma unroll
        for (int w = 0; w < 8; ++w) s += wsum[w];
        atomicAdd(out, s * (2.0f / NB));   // 2 * mean over batches
    }
}

extern "C" void kernel_launch(void* const* d_in, const int* in_sizes, int n_in,
                              void* d_out, int out_size, void* d_ws, size_t ws_size,
                              hipStream_t stream) {
    const float* pc2  = (const float*)d_in[0];
    const float* pc1w = (const float*)d_in[1];
    float* out = (float*)d_out;
    float* partial = (float*)d_ws;                       // 1 MiB
    int*   counter = (int*)((char*)d_ws + (2u << 20));   // 256 B

    // stream-ordered zeroing (graph-capturable memset nodes, R16-proven)
    hipMemsetAsync(out, 0, sizeof(float), stream);
    hipMemsetAsync(counter, 0, NB * QGN * sizeof(int), stream);

    dim3 g1(QGN, RRN, NB);               // (16,8,4) = 512 blocks = 2/CU
    chamfer_fused<<<g1, BT, 0, stream>>>(pc2, pc1w, partial, counter, out);
}

// Round 12
// 73.413 us; speedup vs baseline: 3.7391x; 1.8854x over previous
//
#include <hip/hip_runtime.h>

// ChamferLoss: B=4, C=3, N=M=8192 fp32.
// loss = 2 * mean_b( sum_n min_m ||q_n - r_m||^2 ), clamp >= 0.
// s(n,m) = q.r - 0.5*r^2 via v_mfma_f32_32x32x16_bf16, fp32 split as bf16
// hi+lo across K. Fragment bits identical to R10-R21 (verified absmax 0.0).
//
// ROUND 22: REVERT to R19 (best measured: 73.6us). R21's last-block-
// arrival fusion regressed 73.6 -> 138.4: its device-scope __threadfence
// per block forces an L2 writeback/invalidate on non-coherent per-XCD
// L2s -> ~65us of serialization (counter evidence: chamfer_fused 81.2us,
// VALUBusy 15.7% = 12.7us busy, MfmaUtil 3.9% = 3.1us busy). That busy-
// work number CONFIRMS the R20 clock finding (core ~1.25 GHz): R19's
// main (~18us) carries ~13us of pipe work = ~70% efficiency, <=5us
// theoretical headroom, which 8 structural variants failed to capture.
// Session budget: 40.5us unconditional ws poison fill (83% HBM peak,
// immovable) + main ~18 (floor ~14 at real clock) + reduce ~2.5 +
// harness/dispatch ~12. This revert restores the floor; on confirmation
// (~73-74us) the next step is to declare the roofline.

#define NPTS 8192
#define NB   4
#define RRN  8        // ref ranges (1024 refs each)
#define QGN  16       // q-chunk groups per batch (16 q-chunks each)
#define BT   512

typedef float f32x16 __attribute__((ext_vector_type(16)));
typedef short bf16x8 __attribute__((ext_vector_type(8)));

static __device__ __forceinline__ unsigned int f2bf(float f) {
    unsigned int u = __float_as_uint(f);
    u += 0x7FFF + ((u >> 16) & 1);          // RNE
    return u >> 16;
}
static __device__ __forceinline__ float bf2f(unsigned int s) {
    return __uint_as_float(s << 16);
}

static __device__ __forceinline__ bf16x8 make_bfrag(float x, float y, float z,
                                                    int lane)
{
    unsigned xh = f2bf(x), yh = f2bf(y), zh = f2bf(z);
    unsigned xl = f2bf(x - bf2f(xh));
    unsigned yl = f2bf(y - bf2f(yh));
    unsigned zl = f2bf(z - bf2f(zh));
    // B k0..7 = [xh,xh,xl,yh,yh,yl,zh,zh], k8..15 = [zl,1,1,0,...]
    uint4 bu = (lane < 32)
        ? make_uint4(xh | (xh << 16), xl | (yh << 16),
                     yh | (yl << 16), zh | (zh << 16))
        : make_uint4(zl | (0x3F80u << 16), 0x3F80u, 0u, 0u);
    return __builtin_bit_cast(bf16x8, bu);
}

static __device__ __forceinline__ void proc_chunk(
    uint4 av, bf16x8 bq0, bf16x8 bq1, const f32x16& zero,
    float& rma0, float& rma1, float& rma2, float& rma3,
    float& rmb0, float& rmb1, float& rmb2, float& rmb3)
{
    bf16x8 aa = __builtin_bit_cast(bf16x8, av);
    f32x16 d0 = __builtin_amdgcn_mfma_f32_32x32x16_bf16(aa, bq0, zero, 0, 0, 0);
    f32x16 d1 = __builtin_amdgcn_mfma_f32_32x32x16_bf16(aa, bq1, zero, 0, 0, 0);
    // each line is a 3-input max -> v_max3_f32
    rma0 = fmaxf(rma0, fmaxf(d0[0],  d0[1]));   // rows = refs
    rma0 = fmaxf(rma0, fmaxf(d0[2],  d0[3]));
    rma1 = fmaxf(rma1, fmaxf(d0[4],  d0[5]));
    rma1 = fmaxf(rma1, fmaxf(d0[6],  d0[7]));
    rma2 = fmaxf(rma2, fmaxf(d0[8],  d0[9]));
    rma2 = fmaxf(rma2, fmaxf(d0[10], d0[11]));
    rma3 = fmaxf(rma3, fmaxf(d0[12], d0[13]));
    rma3 = fmaxf(rma3, fmaxf(d0[14], d0[15]));
    rmb0 = fmaxf(rmb0, fmaxf(d1[0],  d1[1]));
    rmb0 = fmaxf(rmb0, fmaxf(d1[2],  d1[3]));
    rmb1 = fmaxf(rmb1, fmaxf(d1[4],  d1[5]));
    rmb1 = fmaxf(rmb1, fmaxf(d1[6],  d1[7]));
    rmb2 = fmaxf(rmb2, fmaxf(d1[8],  d1[9]));
    rmb2 = fmaxf(rmb2, fmaxf(d1[10], d1[11]));
    rmb3 = fmaxf(rmb3, fmaxf(d1[12], d1[13]));
    rmb3 = fmaxf(rmb3, fmaxf(d1[14], d1[15]));
}

// ---- K1: shared-A main kernel ----
// grid (QGN, RRN, NB) = (16,8,4) = 512 blocks = 2/CU, one round.
__global__ __launch_bounds__(BT, 4) void chamfer_main(
    const float* __restrict__ pc2,       // queries [B,3,N]
    const float* __restrict__ pc1w,      // refs    [B,3,N]
    float* __restrict__ partial,         // [B][RRN][NPTS] in ws (1 MiB)
    float* __restrict__ out)
{
    __shared__ uint4 slds[32 * 64];      // 32 KB: A-fragments for 1024 refs
    const int tid  = threadIdx.x;
    const int wave = tid >> 6;
    const int lane = tid & 63;
    const int b    = blockIdx.z;
    const int rr   = blockIdx.y;
    const int qg   = blockIdx.x;

    // zero the accumulator for K2's atomics (K2 is a later dispatch ->
    // stream-ordered; pattern verified in R10)
    if (qg == 0 && rr == 0 && b == 0 && tid == 0) out[0] = 0.0f;

    // stage + convert this range's 1024 refs into A-fragment layout
    // (bit-identical to R11's verified staging conversion)
    const float* refb = pc1w + b * 3 * NPTS + rr * 1024;
#pragma unroll
    for (int j = 0; j < 2; ++j) {
        int i = tid + j * BT;            // 0..1023, coalesced
        float x = refb[i], y = refb[NPTS + i], z = refb[2 * NPTS + i];
        unsigned xh = f2bf(x), yh = f2bf(y), zh = f2bf(z);
        unsigned xl = f2bf(x - bf2f(xh));
        unsigned yl = f2bf(y - bf2f(yh));
        unsigned zl = f2bf(z - bf2f(zh));
        float h = -0.5f * (x * x + y * y + z * z);
        unsigned hh = f2bf(h);
        unsigned hl = f2bf(h - bf2f(hh));
        int c = i >> 5, l32 = i & 31;
        // A k0..7 = [xh,xl,xh,yh,yl,yh,zh,zl], k8..15 = [zh,hh,hl,0,...]
        slds[c * 64 + l32] =
            make_uint4(xh | (xl << 16), xh | (yh << 16),
                       yl | (yh << 16), zh | (zl << 16));
        slds[c * 64 + 32 + l32] = make_uint4(zh | (hh << 16), hl, 0u, 0u);
    }

    // this wave's 2 query chunks (of the block's 16)
    const int qc0 = qg * 16 + wave * 2;
    const float* qb = pc2 + b * 3 * NPTS;
    const int qn0 = qc0 * 32 + (lane & 31);
    const int qn1 = qn0 + 32;
    float x0 = qb[qn0], y0 = qb[NPTS + qn0], z0 = qb[2 * NPTS + qn0];
    float x1 = qb[qn1], y1 = qb[NPTS + qn1], z1 = qb[2 * NPTS + qn1];
    bf16x8 bq0 = make_bfrag(x0, y0, z0, lane);
    bf16x8 bq1 = make_bfrag(x1, y1, z1, lane);

    f32x16 zero;
#pragma unroll
    for (int i = 0; i < 16; ++i) zero[i] = 0.0f;

    float rma0 = -3e38f, rma1 = -3e38f, rma2 = -3e38f, rma3 = -3e38f;
    float rmb0 = -3e38f, rmb1 = -3e38f, rmb2 = -3e38f, rmb3 = -3e38f;

    __syncthreads();                     // LDS image complete

    // all 8 waves share the same 32 chunks; ds_read 1 ahead
    uint4 av = slds[lane];
#pragma unroll 4
    for (int c = 0; c < 32; ++c) {
        uint4 acur = av;
        if (c + 1 < 32)
            av = slds[(c + 1) * 64 + lane];
        proc_chunk(acur, bq0, bq1, zero, rma0, rma1, rma2, rma3,
                   rmb0, rmb1, rmb2, rmb3);
    }

    float rma = fmaxf(fmaxf(rma0, rma1), fmaxf(rma2, rma3));
    float rmb = fmaxf(fmaxf(rmb0, rmb1), fmaxf(rmb2, rmb3));
    // lanes l and l^32 hold the two row-halves of the same query column
    rma = fmaxf(rma, __shfl_xor(rma, 32, 64));
    rmb = fmaxf(rmb, __shfl_xor(rmb, 32, 64));
    float* pb = partial + ((size_t)b * RRN + rr) * NPTS + qc0 * 32;
    if (lane < 32) {
        pb[lane]      = rma;
        pb[32 + lane] = rmb;
    }
}

// ---- K2: finalize (verified R10 structure) ----
__global__ __launch_bounds__(512) void chamfer_reduce(
    const float* __restrict__ pc2,
    const float* __restrict__ partial,
    float* __restrict__ out)
{
    const int g = blockIdx.x * 512 + threadIdx.x;   // query id
    const int b = g >> 13, n = g & 8191;
    float smax = -3e38f;
#pragma unroll
    for (int c = 0; c < RRN; ++c)
        smax = fmaxf(smax, partial[((size_t)b * RRN + c) * NPTS + n]);

    const float* qb = pc2 + b * 3 * NPTS;
    float qx = qb[n], qy = qb[NPTS + n], qz = qb[2 * NPTS + n];
    float q2 = qx * qx + qy * qy + qz * qz;
    float d = fmaxf(q2 - 2.0f * smax, 0.0f);

#pragma unroll
    for (int off = 32; off > 0; off >>= 1)
        d += __shfl_down(d, off, 64);

    __shared__ float wsum[8];
    const int lane = threadIdx.x & 63;
    const int wid  = threadIdx.x >> 6;
    if (lane == 0) wsum[wid] = d;
    __syncthreads();
    if (threadIdx.x == 0) {
        float s = 0.0f;
#pragma unroll
        for (int w = 0; w < 8; ++w) s += wsum[w];
        atomicAdd(out, s * (2.0f / NB));   // 2 * mean over batches
    }
}

extern "C" void kernel_launch(void* const* d_in, const int* in_sizes, int n_in,
                              void* d_out, int out_size, void* d_ws, size_t ws_size,
                              hipStream_t stream) {
    const float* pc2  = (const float*)d_in[0];
    const float* pc1w = (const float*)d_in[1];
    float* out = (float*)d_out;
    float* partial = (float*)d_ws;       // B * RRN * NPTS * 4 = 1 MiB

    dim3 g1(QGN, RRN, NB);               // (16,8,4) = 512 blocks = 2/CU
    chamfer_main<<<g1, BT, 0, stream>>>(pc2, pc1w, partial, out);
    chamfer_reduce<<<NB * NPTS / 512, 512, 0, stream>>>(pc2, partial, out);
}